// Round 3
// baseline (2647.874 us; speedup 1.0000x reference)
//
#include <hip/hip_runtime.h>

// Problem constants (from reference setup_inputs)
constexpr int kB    = 256;
constexpr int kT    = 2048;
constexpr int kI    = 32;
constexpr int kH    = 64;
constexpr int kO    = 16;
constexpr int kPadL = 2;
constexpr int kPadR = 3;
constexpr int kTp   = kT + kPadL + kPadR;      // 2053 recurrence steps
constexpr int kNB   = 16;                      // batches per block = MFMA N
constexpr int kNBLK = kB / kNB;                // 16 blocks
constexpr int kCT   = 12;                      // timesteps per producer chunk
constexpr int kNC   = (kTp + kCT - 1) / kCT;   // 172 chunks (tail = 1 step)
constexpr int kHP   = 68;                      // padded hidden stride in LDS
constexpr float kS  = 1.4426950408889634f;     // log2(e), folded into weights

static_assert((kNC - 1) * kCT + 1 == kTp, "tail must be exactly 1 step");

typedef float    f32x4  __attribute__((ext_vector_type(4)));
typedef float    v2f    __attribute__((ext_vector_type(2)));
typedef unsigned uint4v __attribute__((ext_vector_type(4)));
typedef __fp16   h8     __attribute__((ext_vector_type(8)));
typedef __fp16   h2     __attribute__((ext_vector_type(2)));

__device__ __forceinline__ void pk_fma(v2f& d, v2f a, v2f b) {
  asm("v_pk_fma_f32 %0, %1, %2, %0" : "+v"(d) : "v"(a), "v"(b));
}
__device__ __forceinline__ void pk_add(v2f& d, v2f a) {
  asm("v_pk_add_f32 %0, %0, %1" : "+v"(d) : "v"(a));
}
__device__ __forceinline__ float exp2_fast(float x) {
#if __has_builtin(__builtin_amdgcn_exp2f)
  return __builtin_amdgcn_exp2f(x);
#else
  return exp2f(x);
#endif
}
__device__ __forceinline__ h2 pkrtz(float a, float b) {
  return __builtin_bit_cast(h2, __builtin_amdgcn_cvt_pkrtz(a, b));
}
// Pack 4 half2 into one half8 (elem order a.x,a.y,b.x,b.y,c.x,c.y,d.x,d.y)
__device__ __forceinline__ h8 h8_pack(h2 a, h2 b, h2 c, h2 d) {
  uint4v u = { __builtin_bit_cast(unsigned, a), __builtin_bit_cast(unsigned, b),
               __builtin_bit_cast(unsigned, c), __builtin_bit_cast(unsigned, d) };
  return __builtin_bit_cast(h8, u);
}

// Block = 8 waves for 16 batch elements.
//   wave 0 (consumer): serial recurrence via v_mfma_f32_16x16x32_f16 (the
//     gfx950 16x16x32 family whose C/D layout is HW-verified:
//     col=lane&15, row=4*(lane>>4)+reg).
//     State r (= (1-h)/2 = sigmoid(-2z)) lives in REGISTERS. The D-tiles of
//     step t ARE the B-operands of step t+1: B's non-K index = lane&15
//     (= batch = D's col), and the K-placement is chosen to be exactly the
//     order the D-tiles deliver (HW pairs A-elem (g,i) with B-elem (g,i), so
//     any k-placement is correct as long as A is gathered with the SAME
//     placement — removes all internal-k-wiring assumptions):
//       Bf[kk] elems 0-3 = D-tile(2kk)   regs 0-3 -> h = 32kk      + 4g + i
//       Bf[kk] elems 4-7 = D-tile(2kk+1) regs 0-3 -> h = 32kk + 16 + 4g + i
//     A[m][kk] gathered from W2 = -4*kS*W_hh with identical placement.
//     z' = xin' (C-init from LDS) + sum A·r ; t = exp2(z'); r = rcp(1+t);
//     h_sum = Tp - 2*sum(r).
//   waves 1..7 (producers): xin'[s][b][h] = 2*kS*(b_ih+b_hh+rowsum+W_ih[h]·x_t)
//     double-buffered in LDS, one chunk (12 steps) ahead. Pad steps: bias only.
__global__ __launch_bounds__(512, 2) void rnn_mfma(
    const float* __restrict__ x,
    const float* __restrict__ W_ih,
    const float* __restrict__ W_hh,
    const float* __restrict__ b_ih,
    const float* __restrict__ b_hh,
    const float* __restrict__ W_fc,
    const float* __restrict__ b_fc,
    float* __restrict__ out)
{
  const int b0   = blockIdx.x * kNB;
  const int lane = threadIdx.x & 63;
  const int wave = threadIdx.x >> 6;

  __shared__ __align__(16) float xinbuf[2][kCT][kNB][kHP];  // 104448 B

  if (wave != 0) {
    // ======================= producers (waves 1..7) =======================
    float rowsum = 0.f;
#pragma unroll
    for (int j = 0; j < kH; j += 4) {
      float4 v = *(const float4*)(W_hh + lane * kH + j);
      rowsum += (v.x + v.y) + (v.z + v.w);
    }
    const float bias2 = 2.f * kS * (b_ih[lane] + b_hh[lane] + rowsum);
    v2f wi2[kI / 2];
#pragma unroll
    for (int i = 0; i < kI; i += 4) {
      float4 v = *(const float4*)(W_ih + lane * kI + i);
      wi2[i / 2 + 0] = v2f{2.f * kS * v.x, 2.f * kS * v.y};
      wi2[i / 2 + 1] = v2f{2.f * kS * v.z, 2.f * kS * v.w};
    }
    const int pw = wave - 1;  // 0..6

    auto fill = [&](int c) {
      const int s0 = c * kCT;
      for (int bi = pw; bi < kNB; bi += 7) {
        const float* xb = x + (size_t)(b0 + bi) * kT * kI;
        for (int tl = 0; tl < kCT; ++tl) {
          const int s = s0 + tl;
          if (s >= kTp) break;
          float v = bias2;
          if (s >= kPadL && s < kPadL + kT) {
            const float4* row = (const float4*)(xb + (size_t)(s - kPadL) * kI);
            v2f a0 = v2f{0.f, 0.f}, a1 = v2f{0.f, 0.f};
#pragma unroll
            for (int i2 = 0; i2 < 8; ++i2) {
              float4 q = row[i2];  // broadcast loads (uniform addr -> L1)
              pk_fma(a0, wi2[2 * i2 + 0], v2f{q.x, q.y});
              pk_fma(a1, wi2[2 * i2 + 1], v2f{q.z, q.w});
            }
            v += (a0.x + a0.y) + (a1.x + a1.y);
          }
          xinbuf[c & 1][tl][bi][lane] = v;
        }
      }
    };

    fill(0);
    __syncthreads();  // chunk 0 ready
    for (int c = 0; c < kNC; ++c) {
      if (c + 1 < kNC) fill(c + 1);
      __syncthreads();  // consumer done with buf c&1
    }
    return;
  }

  // ========================= consumer (wave 0) =========================
  __builtin_amdgcn_s_setprio(1);  // favor the serial-critical wave
  const int col = lane & 15;      // MFMA col (batch) / A-row within tile
  const int g   = lane >> 4;      // lane group

  const float c4 = -4.f * kS;
  // A2[m][kk] gathered with the SAME (g,i) placement the D-tiles deliver:
  // elems 0-3: W2[16m+col][32kk + 4g + 0..3]; elems 4-7: +16.
  h8 A2[4][2];
#pragma unroll
  for (int m = 0; m < 4; ++m)
#pragma unroll
    for (int kk = 0; kk < 2; ++kk) {
      const float* wp = W_hh + (16 * m + col) * kH + 32 * kk + 4 * g;
      float4 lo = *(const float4*)(wp);
      float4 hi = *(const float4*)(wp + 16);
      A2[m][kk] = h8_pack(pkrtz(c4 * lo.x, c4 * lo.y), pkrtz(c4 * lo.z, c4 * lo.w),
                          pkrtz(c4 * hi.x, c4 * hi.y), pkrtz(c4 * hi.z, c4 * hi.w));
    }

  // B fragments = r from previous step; h0 = 0 -> r = 0.5 everywhere.
  h8 Bf[2];
#pragma unroll
  for (int kk = 0; kk < 2; ++kk)
    Bf[kk] = h8{(__fp16)0.5f, (__fp16)0.5f, (__fp16)0.5f, (__fp16)0.5f,
                (__fp16)0.5f, (__fp16)0.5f, (__fp16)0.5f, (__fp16)0.5f};

  v2f rs2[8];  // rsum pairs: rs2[2m+p] = rows 16m+4g+{2p,2p+1}
#pragma unroll
  for (int i = 0; i < 8; ++i) rs2[i] = v2f{0.f, 0.f};
  const v2f ones = v2f{1.f, 1.f};

  auto ldx = [&](f32x4 (&xv)[4], int buf, int tl) {
    const float* base = &xinbuf[buf][tl][col][4 * g];
#pragma unroll
    for (int m = 0; m < 4; ++m)
      xv[m] = *(const f32x4*)(base + 16 * m);  // ds_read_b128
  };

  auto step = [&](const f32x4 (&xv)[4]) {
    f32x4 acc[4];
    // K-block 0 (C-init = xin'), then K-block 1 — 2 dependent MFMA stages.
#pragma unroll
    for (int m = 0; m < 4; ++m)
      acc[m] = __builtin_amdgcn_mfma_f32_16x16x32_f16(A2[m][0], Bf[0], xv[m], 0, 0, 0);
#pragma unroll
    for (int m = 0; m < 4; ++m)
      acc[m] = __builtin_amdgcn_mfma_f32_16x16x32_f16(A2[m][1], Bf[1], acc[m], 0, 0, 0);
    // tanh tail (parallel across tiles on the VALU/trans pipes)
    h2 rp01[4], rp23[4];
#pragma unroll
    for (int m = 0; m < 4; ++m) {
      v2f e01, e23;
      e01.x = exp2_fast(acc[m].x);
      e01.y = exp2_fast(acc[m].y);
      e23.x = exp2_fast(acc[m].z);
      e23.y = exp2_fast(acc[m].w);
      pk_add(e01, ones);   // 1 + t   (inf -> r = 0 via rcp)
      pk_add(e23, ones);
      v2f r01, r23;
      r01.x = __builtin_amdgcn_rcpf(e01.x);
      r01.y = __builtin_amdgcn_rcpf(e01.y);
      r23.x = __builtin_amdgcn_rcpf(e23.x);
      r23.y = __builtin_amdgcn_rcpf(e23.y);
      pk_add(rs2[2 * m + 0], r01);
      pk_add(rs2[2 * m + 1], r23);
      rp01[m] = pkrtz(r01.x, r01.y);
      rp23[m] = pkrtz(r23.x, r23.y);
    }
    Bf[0] = h8_pack(rp01[0], rp23[0], rp01[1], rp23[1]);  // tiles 0,1 -> k 0..31
    Bf[1] = h8_pack(rp01[2], rp23[2], rp01[3], rp23[3]);  // tiles 2,3 -> k 32..63
  };

  __syncthreads();  // chunk 0 ready
  f32x4 xa[4], xb[4];
  for (int c = 0; c < kNC; ++c) {
    const int buf = c & 1;
    if (c < kNC - 1) {
      ldx(xa, buf, 0);
      for (int u = 0; u < kCT / 2 - 1; ++u) {
        ldx(xb, buf, 2 * u + 1);  // prefetch next step (off critical path)
        step(xa);
        ldx(xa, buf, 2 * u + 2);
        step(xb);
      }
      ldx(xb, buf, kCT - 1);
      step(xa);
      step(xb);
    } else {
      ldx(xa, buf, 0);
      step(xa);  // tail chunk: exactly 1 step
    }
    __syncthreads();
  }

  // ---- epilogue: mean over Tp, FC (16x64) + ReLU (single wave) ----
  float* aggb = &xinbuf[0][0][0][0];  // reuse as agg[b][kHP]
  const float c2 = 2.f / (float)kTp;
#pragma unroll
  for (int m = 0; m < 4; ++m) {
    f32x4 v;
    v.x = 1.f - c2 * rs2[2 * m + 0].x;
    v.y = 1.f - c2 * rs2[2 * m + 0].y;
    v.z = 1.f - c2 * rs2[2 * m + 1].x;
    v.w = 1.f - c2 * rs2[2 * m + 1].y;
    *(f32x4*)&aggb[col * kHP + 16 * m + 4 * g] = v;
  }
  asm volatile("s_waitcnt lgkmcnt(0)" ::: "memory");  // single wave, in-order DS
  __builtin_amdgcn_sched_barrier(0);                  // pin load/store order
  float4 bfc = *(const float4*)(b_fc + 4 * g);
  float oa[4] = {bfc.x, bfc.y, bfc.z, bfc.w};
#pragma unroll
  for (int h4i = 0; h4i < kH / 4; ++h4i) {
    f32x4 av = *(const f32x4*)&aggb[col * kHP + 4 * h4i];
#pragma unroll
    for (int oi = 0; oi < 4; ++oi) {
      float4 wv = *(const float4*)(W_fc + (4 * g + oi) * kH + 4 * h4i);
      oa[oi] = fmaf(wv.x, av.x, fmaf(wv.y, av.y, fmaf(wv.z, av.z, fmaf(wv.w, av.w, oa[oi]))));
    }
  }
  float4 o4;
  o4.x = fmaxf(oa[0], 0.f);
  o4.y = fmaxf(oa[1], 0.f);
  o4.z = fmaxf(oa[2], 0.f);
  o4.w = fmaxf(oa[3], 0.f);
  *(float4*)(out + (size_t)(b0 + col) * kO + 4 * g) = o4;
}

extern "C" void kernel_launch(void* const* d_in, const int* in_sizes, int n_in,
                              void* d_out, int out_size, void* d_ws, size_t ws_size,
                              hipStream_t stream) {
  const float* x    = (const float*)d_in[0];
  const float* W_ih = (const float*)d_in[1];
  const float* W_hh = (const float*)d_in[2];
  const float* b_ih = (const float*)d_in[3];
  const float* b_hh = (const float*)d_in[4];
  const float* W_fc = (const float*)d_in[5];
  const float* b_fc = (const float*)d_in[6];
  float* out = (float*)d_out;

  rnn_mfma<<<dim3(kNBLK), dim3(512), 0, stream>>>(x, W_ih, W_hh, b_ih, b_hh,
                                                  W_fc, b_fc, out);
}